// Round 4
// baseline (302.121 us; speedup 1.0000x reference)
//
#include <hip/hip_runtime.h>

// ---------------------------------------------------------------------------
// CausalSelfAttention (B=1, T=2048, DIM=1024, H=8, hd=128, scale=0.12)
// R4: attention rebuilt around the S^T trick + 16x16x16 PV:
//   - S^T = K*Q^T (16x16x32 MFMA, K from LDS, Q in regs)
//   - P exits in C-layout == B-operand layout of mfma_f32_16x16x16_bf16
//     -> PV directly, no shuffles / no p_sh / no LDS round-trip
//   - V A-frags read straight from global vt[h][d][t] (L1/L2 resident)
//   - K double-buffered in LDS via async global_load_lds (XOR swizzle),
//     prefetch issued right after the barrier -> 1 barrier/iter, loads
//     overlap compute.
// MFMA layouts (m89/m91/m120): A[m=lane&15][k=quad*8+j] (x32) /
//   A[m=lane&15][k=quad*4+j] (x16); B same with n=lane&15;
//   C/D: row=quad*4+reg, col=lane&15  (quad=lane>>4)
// ---------------------------------------------------------------------------

typedef __attribute__((ext_vector_type(8))) short short8;      // 8 bf16
typedef __attribute__((ext_vector_type(4))) short short4b;     // 4 bf16
typedef __attribute__((ext_vector_type(4))) float fx4;         // MFMA acc
typedef __attribute__((ext_vector_type(8))) unsigned short ushort8;
typedef __attribute__((ext_vector_type(4))) unsigned short ushort4v;
typedef __attribute__((ext_vector_type(2))) unsigned short ushort2v;
typedef __attribute__((ext_vector_type(4))) float float4v;

#define T_SEQ 2048
#define NH 8
#define HD 128
#define NCH 5      // kv chunks per q-tile
#define CHW 7      // kv-tiles per chunk

__device__ __forceinline__ unsigned short f2bf(float f) {
  union { float f; unsigned u; } v; v.f = f;
  unsigned u = v.u;
  u += 0x7fffu + ((u >> 16) & 1u);        // RNE, finite inputs only
  return (unsigned short)(u >> 16);
}
__device__ __forceinline__ short bf_t(float f) {  // truncate (fast)
  union { float f; unsigned u; } v; v.f = f;
  return (short)(v.u >> 16);
}
__device__ __forceinline__ float bf2f(unsigned short h) {
  union { unsigned u; float f; } v; v.u = ((unsigned)h) << 16;
  return v.f;
}

// async global->LDS, 16B/lane; LDS dest = wave-uniform base + lane*16
typedef __attribute__((address_space(1))) unsigned int glb_u32;
typedef __attribute__((address_space(3))) unsigned int lds_u32;
__device__ __forceinline__ void gl_lds16(const unsigned short* g, unsigned short* l) {
  __builtin_amdgcn_global_load_lds((const glb_u32*)g, (lds_u32*)l, 16, 0, 0);
}

// ---------------------------------------------------------------------------
// Kernel 0: cast x (2M), qkv_w (3M), c_proj_w (1M) fp32 -> bf16 contiguous.
// ---------------------------------------------------------------------------
__global__ __launch_bounds__(256) void cast3_kernel(
    const float* __restrict__ x, const float* __restrict__ w1,
    const float* __restrict__ w2, unsigned short* __restrict__ o) {
  long q = (long)blockIdx.x * 256 + threadIdx.x;   // quad index
  const float* src;
  if (q < 524288)        src = x  + 4 * q;
  else if (q < 1310720)  src = w1 + 4 * (q - 524288);
  else                   src = w2 + 4 * (q - 1310720);
  float4v v = *(const float4v*)src;
  ushort4v r;
  r[0] = f2bf(v[0]); r[1] = f2bf(v[1]); r[2] = f2bf(v[2]); r[3] = f2bf(v[3]);
  *(ushort4v*)(o + 4 * q) = r;
}

// ---------------------------------------------------------------------------
// GEMM (BT): C[M,N] = A[M,K]*B[N,K]^T, bf16 in / fp32 acc. Tile 128 x BN,
// BK=32, 4 waves (2x2, wave tile 64 x BN/2). global_load_lds width=16;
// LDS unpadded [rows][32]; 16B chunk c of row m at pos c ^ ((m>>1)&3).
// ---------------------------------------------------------------------------
template <bool OUT_BF16, int BN>
__global__ __launch_bounds__(256) void gemm_bt2(
    const unsigned short* __restrict__ A, const unsigned short* __restrict__ B,
    void* __restrict__ Cp, int M, int N, int K) {
  constexpr int NT = BN / 32;                 // n-tiles per wave
  constexpr int NLOAD = (512 + BN * 4) / 256; // gl_lds16 per thread
  __shared__ unsigned short a_sh[128 * 32];
  __shared__ unsigned short b_sh[BN * 32];
  const int tid = threadIdx.x;
  const int wave = tid >> 6, lane = tid & 63;
  const int ln = lane & 15, quad = lane >> 4;
  const int wm = wave & 1, wn = wave >> 1;
  const long arow0 = (long)blockIdx.y * 128;
  const long brow0 = (long)blockIdx.x * BN;

  const unsigned short* gsrc[NLOAD];
  unsigned short* ldst[NLOAD];
  for (int i = 0; i < NLOAD; ++i) {
    int s = wave * NLOAD + i;             // segment (wave-uniform)
    int li = s * 64 + lane;               // linear chunk
    int isB = li >= 512;
    int ci = isB ? li - 512 : li;
    int m = ci >> 2, p = ci & 3;
    int cch = p ^ ((m >> 1) & 3);
    const unsigned short* Gb = isB ? (B + brow0 * (long)K) : (A + arow0 * (long)K);
    gsrc[i] = Gb + (long)m * K + cch * 8;
    ldst[i] = isB ? (b_sh + (s - 8) * 512) : (a_sh + s * 512);
  }

  fx4 acc[4][NT] = {};
  for (int k0 = 0; k0 < K; k0 += 32) {
    __syncthreads();
    for (int i = 0; i < NLOAD; ++i)
      gl_lds16(gsrc[i] + k0, ldst[i]);
    __syncthreads();
    short8 af[4], bfr[NT];
    for (int mt = 0; mt < 4; ++mt) {
      int m = wm * 64 + mt * 16 + ln;
      int pos = quad ^ ((m >> 1) & 3);
      af[mt] = *(const short8*)&a_sh[m * 32 + pos * 8];
    }
    for (int nt = 0; nt < NT; ++nt) {
      int m = wn * (BN / 2) + nt * 16 + ln;
      int pos = quad ^ ((m >> 1) & 3);
      bfr[nt] = *(const short8*)&b_sh[m * 32 + pos * 8];
    }
    for (int mt = 0; mt < 4; ++mt)
      for (int nt = 0; nt < NT; ++nt)
        acc[mt][nt] = __builtin_amdgcn_mfma_f32_16x16x32_bf16(
            af[mt], bfr[nt], acc[mt][nt], 0, 0, 0);
  }
  for (int mt = 0; mt < 4; ++mt)
    for (int nt = 0; nt < NT; ++nt)
      for (int r = 0; r < 4; ++r) {
        long row = arow0 + wm * 64 + mt * 16 + quad * 4 + r;
        long col = brow0 + wn * (BN / 2) + nt * 16 + ln;
        float v = acc[mt][nt][r];
        if constexpr (OUT_BF16)
          ((unsigned short*)Cp)[row * N + col] = f2bf(v);
        else
          ((float*)Cp)[row * N + col] = v;
      }
}

// ---------------------------------------------------------------------------
// Kernel 2a: per-head RMSNorm + rotary for q,k. qhat/khat: [h][t][d] bf16.
// ---------------------------------------------------------------------------
__global__ __launch_bounds__(256) void qk_norm_rope(
    const unsigned short* __restrict__ qkv, unsigned short* __restrict__ qh,
    unsigned short* __restrict__ kh) {
  const int t = blockIdx.x;
  const int tid = threadIdx.x;
  const int h = tid >> 5, c = tid & 31;
  float cv[2], sv[2];
  for (int u = 0; u < 2; ++u) {
    int dd = 2 * c + u;
    if (dd < 32) {
      float ang = exp2f(-10.0f * (float)dd / 31.0f);  // (1/1024)^(dd/31)
      float th = (float)t * ang;
      sv[u] = __sinf(th); cv[u] = __cosf(th);
    } else { sv[u] = 0.f; cv[u] = 1.f; }
  }
  for (int which = 0; which < 2; ++which) {           // 0 = q, 1 = k
    const unsigned short* src = qkv + (long)t * 3072 + which * 1024 + h * 128;
    ushort2v aa = *(const ushort2v*)(src + 2 * c);
    ushort2v bb = *(const ushort2v*)(src + 64 + 2 * c);
    float x1[2] = { bf2f(aa[0]), bf2f(aa[1]) };
    float x2[2] = { bf2f(bb[0]), bf2f(bb[1]) };
    float ss = x1[0]*x1[0] + x1[1]*x1[1] + x2[0]*x2[0] + x2[1]*x2[1];
    for (int off = 1; off < 32; off <<= 1) ss += __shfl_xor(ss, off);
    float rn = rsqrtf(ss * (1.0f / 128.0f) + 1.1920929e-7f);
    ushort2v o1, o2;
    for (int u = 0; u < 2; ++u) {
      float y1 = ( x1[u] * cv[u] + x2[u] * sv[u]) * rn;
      float y2 = (-x1[u] * sv[u] + x2[u] * cv[u]) * rn;
      o1[u] = f2bf(y1); o2[u] = f2bf(y2);
    }
    unsigned short* dst = (which ? kh : qh) + ((long)h * T_SEQ + t) * 128;
    *(ushort2v*)(dst + 2 * c) = o1;
    *(ushort2v*)(dst + 64 + 2 * c) = o2;
  }
}

// ---------------------------------------------------------------------------
// Kernel 2b: v = l0*v + l1*ve, transpose to vt[h][d][t] bf16 via LDS.
// ---------------------------------------------------------------------------
__global__ __launch_bounds__(256) void v_combine_t(
    const unsigned short* __restrict__ qkv, const float* __restrict__ ve,
    const float* __restrict__ lambdas, unsigned short* __restrict__ vt) {
  __shared__ unsigned short lt[128 * 72];
  const int tt = blockIdx.x, h = blockIdx.y;
  const int tid = threadIdx.x;
  const float l0 = lambdas[0], l1 = lambdas[1];
  const int r = tid >> 2, cb = (tid & 3) * 32;
  const unsigned short* vs = qkv + (long)(tt * 64 + r) * 3072 + 2048 + h * 128 + cb;
  const float* es = ve + (long)(tt * 64 + r) * 1024 + h * 128 + cb;
  ushort8 vv[4];
  for (int q = 0; q < 4; ++q) vv[q] = *(const ushort8*)(vs + 8 * q);
  float4v ee[8];
  for (int q = 0; q < 8; ++q) ee[q] = *(const float4v*)(es + 4 * q);
  for (int j = 0; j < 32; ++j) {
    float v = bf2f(vv[j >> 3][j & 7]) * l0 + ee[j >> 2][j & 3] * l1;
    lt[(cb + j) * 72 + r] = f2bf(v);
  }
  __syncthreads();
  const int d = tid >> 1, half = (tid & 1) * 32;
  unsigned short* dst = vt + ((long)h * HD + d) * T_SEQ + tt * 64 + half;
  const unsigned short* srcl = &lt[d * 72 + half];
  *(ushort8*)(dst)      = *(const ushort8*)(srcl);
  *(ushort8*)(dst + 8)  = *(const ushort8*)(srcl + 8);
  *(ushort8*)(dst + 16) = *(const ushort8*)(srcl + 16);
  *(ushort8*)(dst + 24) = *(const ushort8*)(srcl + 24);
}

// ---------------------------------------------------------------------------
// Kernel 3a: chunked flash attention partials (R4 structure).
// Grid (qt=32, h=8, ch=NCH); chunk covers kv-tiles [CHW*ch, min(+CHW-1, qt)].
// S^T = K*Q^T via 16x16x32 (A=K from LDS, B=Q regs) -> C rows=kv, cols=q=ln.
// p = exp2(s*0.12*log2e - 16*log2e)  (fixed-max; |s|<=15.4), l per-lane.
// PV: accy[dt] = mfma_16x16x16(Vfrag, pack(p), accy[dt]) -- P already in
// B-layout; Vfrag (8B) read directly from global vt[h][d][t].
// K LDS: double-buffered [64][128] shorts, 16B chunk c of row m stored at
// pos c ^ (m&15); staged by async global_load_lds, prefetch after barrier.
// ---------------------------------------------------------------------------
#define ATT_C1 0.17312340490667562f   // 0.12 * log2(e)
#define ATT_C2 23.083120654223415f    // 16   * log2(e)

__global__ __launch_bounds__(256, 4) void attn_part(
    const unsigned short* __restrict__ qh, const unsigned short* __restrict__ kh,
    const unsigned short* __restrict__ vt, unsigned short* __restrict__ Yp,
    float* __restrict__ lp) {
  __shared__ unsigned short kbuf[2][8192];    // 2 x 16KB
  const int tid = threadIdx.x;
  const int wave = tid >> 6, lane = tid & 63;
  const int ln = lane & 15, quad = lane >> 4;
  const int qt = blockIdx.x, h = blockIdx.y, ch = blockIdx.z;
  const int j0 = ch * CHW;
  if (j0 > qt) return;                        // uniform per block
  const int j1 = min(j0 + CHW - 1, qt);
  const int qrow0 = qt * 64 + wave * 16;
  const int qg = qrow0 + ln;                  // this lane's q row

  short8 qf[4];
  {
    const unsigned short* qbase = qh + ((long)h * T_SEQ + qg) * 128;
    for (int kc = 0; kc < 4; ++kc)
      qf[kc] = *(const short8*)(qbase + kc * 32 + quad * 8);
  }
  fx4 accy[8] = {};                           // Y^T: 8 d-tiles x 4 regs
  float l_loc = 0.f;

  // K staging: 4 segments/wave, 64 chunks (16B) each; swizzled source.
  const unsigned short* kg[4];
  unsigned short* kl[4];
  for (int i = 0; i < 4; ++i) {
    int s = wave * 4 + i;
    int li = s * 64 + lane;
    int row = li >> 4, pos = li & 15;
    int c = pos ^ (row & 15);
    kg[i] = kh + ((long)h * T_SEQ + row) * 128 + c * 8;
    kl[i] = &kbuf[0][s * 512];
  }
  // V base for A-frags: row = dt*16+ln, k-bytes at kt*16+quad*4 (+jt*64)
  const unsigned short* vbase = vt + ((long)h * HD + ln) * T_SEQ + quad * 4;

  // initial stage into buffer 0
  for (int i = 0; i < 4; ++i) gl_lds16(kg[i] + (long)j0 * 8192, kl[i]);

  int cur = 0;
  for (int jt = j0; jt <= j1; ++jt, cur ^= 1) {
    __syncthreads();                          // publishes buffer `cur`
    if (jt < j1) {                            // prefetch next into other buf
      for (int i = 0; i < 4; ++i)
        gl_lds16(kg[i] + (long)(jt + 1) * 8192, kl[i] + (cur ^ 1) * 8192);
    }
    const unsigned short* kb_ = &kbuf[cur][0];

    // S^T tiles: kt -> kv rows [kt*16, kt*16+16), cols q (=ln)
    fx4 s4[4];
    for (int kt = 0; kt < 4; ++kt) {
      fx4 c = {0.f, 0.f, 0.f, 0.f};
      for (int kc = 0; kc < 4; ++kc) {
        int pos = (kc * 4 + quad) ^ ln;
        short8 kbf = *(const short8*)&kb_[(kt * 16 + ln) * 128 + pos * 8];
        c = __builtin_amdgcn_mfma_f32_16x16x32_bf16(kbf, qf[kc], c, 0, 0, 0);
      }
      s4[kt] = c;
    }
    const bool diag = (jt == qt);
    const unsigned short* vj = vbase + jt * 64;
    for (int kt = 0; kt < 4; ++kt) {
      float p[4];
      for (int r = 0; r < 4; ++r) {
        float pv = exp2f(fmaf(s4[kt][r], ATT_C1, -ATT_C2));
        if (diag && (jt * 64 + kt * 16 + quad * 4 + r) > qg) pv = 0.f;
        p[r] = pv;
      }
      l_loc += (p[0] + p[1]) + (p[2] + p[3]);
      short4b pb = { bf_t(p[0]), bf_t(p[1]), bf_t(p[2]), bf_t(p[3]) };
      const unsigned short* vk = vj + kt * 16;
      for (int dt = 0; dt < 8; ++dt) {
        short4b va = *(const short4b*)(vk + dt * 16 * T_SEQ);
        accy[dt] = __builtin_amdgcn_mfma_f32_16x16x16bf16_1k(
            va, pb, accy[dt], 0, 0, 0);
      }
    }
  }

  // reduce l across quads (lanes ln, ln+16, ln+32, ln+48)
  l_loc += __shfl_xor(l_loc, 16);
  l_loc += __shfl_xor(l_loc, 32);
  const long pidx = (long)((h * 32 + qt) * NCH + ch);
  if (quad == 0) lp[pidx * 64 + wave * 16 + ln] = l_loc;
  unsigned short* yb = Yp + pidx * 8192 + (wave * 16 + ln) * 128;
  for (int dt = 0; dt < 8; ++dt) {
    ushort4v o;
    for (int r = 0; r < 4; ++r) o[r] = (unsigned short)f2bf(accy[dt][r]);
    *(ushort4v*)(yb + dt * 16 + quad * 4) = o;
  }
}

// ---------------------------------------------------------------------------
// Kernel 3b: combine partials: Y = (sum_c Yp) / (sum_c lp) -> ybf [t][h*128+d].
// ---------------------------------------------------------------------------
__global__ __launch_bounds__(256) void attn_combine(
    const unsigned short* __restrict__ Yp, const float* __restrict__ lp,
    unsigned short* __restrict__ y) {
  const int qt = blockIdx.x, h = blockIdx.y;
  const int tid = threadIdx.x;
  const int row = tid >> 2, cb = (tid & 3) * 32;
  const int nc = qt / CHW + 1;
  float acc[32];
  for (int j = 0; j < 32; ++j) acc[j] = 0.f;
  float ltot = 0.f;
  for (int c = 0; c < nc; ++c) {
    long pidx = (long)((h * 32 + qt) * NCH + c);
    const unsigned short* ys = Yp + pidx * 8192 + row * 128 + cb;
    ltot += lp[pidx * 64 + row];
    for (int q8 = 0; q8 < 4; ++q8) {
      ushort8 v = *(const ushort8*)(ys + q8 * 8);
      for (int j = 0; j < 8; ++j) acc[q8 * 8 + j] += bf2f(v[j]);
    }
  }
  float inv = 1.f / ltot;
  unsigned short* dst = y + (long)(qt * 64 + row) * 1024 + h * 128 + cb;
  for (int q8 = 0; q8 < 4; ++q8) {
    ushort8 o;
    for (int j = 0; j < 8; ++j) o[j] = f2bf(acc[q8 * 8 + j] * inv);
    *(ushort8*)(dst + q8 * 8) = o;
  }
}

// ---------------------------------------------------------------------------
// Workspace layout (bytes), ~42 MB. Attention partials reuse dead regions:
//   0        : qkv_bf [2048][3072] bf16 (12MB) | attn: Yp bf16 (1280x16KB =
//   12582912 : x_bf   (4MB)                    |   20.97MB, spans 0..20.97M)
//   16777216 : wqkv   (6MB)                    | attn: lp fp32 @20971520
//   23068672 : wproj  (2MB, live until GEMM2)
//   25165824 : qhat [8][2048][128] (4MB)
//   29360128 : khat (4MB)
//   33554432 : vt   [8][128][2048] (4MB)
//   37748736 : ybf  [2048][1024] (4MB)
// ---------------------------------------------------------------------------
extern "C" void kernel_launch(void* const* d_in, const int* in_sizes, int n_in,
                              void* d_out, int out_size, void* d_ws, size_t ws_size,
                              hipStream_t stream) {
  const float* x       = (const float*)d_in[0];
  const float* ve      = (const float*)d_in[1];
  const float* qkv_w   = (const float*)d_in[2];
  const float* lambdas = (const float*)d_in[3];
  const float* c_proj  = (const float*)d_in[4];
  char* ws = (char*)d_ws;
  unsigned short* qkv_bf = (unsigned short*)(ws);
  unsigned short* x_bf   = (unsigned short*)(ws + 12582912);
  unsigned short* wqkv   = (unsigned short*)(ws + 16777216);
  unsigned short* wproj  = (unsigned short*)(ws + 23068672);
  unsigned short* qhat   = (unsigned short*)(ws + 25165824);
  unsigned short* khat   = (unsigned short*)(ws + 29360128);
  unsigned short* vtb    = (unsigned short*)(ws + 33554432);
  unsigned short* ybf    = (unsigned short*)(ws + 37748736);
  unsigned short* Yp     = (unsigned short*)(ws);              // reuse, 21MB
  float*          lpart  = (float*)(ws + 20971520);            // reuse, 328KB
  float* out = (float*)d_out;

  cast3_kernel<<<6144, 256, 0, stream>>>(x, qkv_w, c_proj, x_bf);
  gemm_bt2<true, 64><<<dim3(48, 16), 256, 0, stream>>>(x_bf, wqkv, qkv_bf, 2048, 3072, 1024);
  qk_norm_rope<<<2048, 256, 0, stream>>>(qkv_bf, qhat, khat);
  v_combine_t<<<dim3(32, 8), 256, 0, stream>>>(qkv_bf, ve, lambdas, vtb);
  attn_part<<<dim3(32, 8, NCH), 256, 0, stream>>>(qhat, khat, vtb, Yp, lpart);
  attn_combine<<<dim3(32, 8), 256, 0, stream>>>(Yp, lpart, ybf);
  gemm_bt2<false, 64><<<dim3(16, 16), 256, 0, stream>>>(ybf, wproj, out, 2048, 1024, 1024);
}

// Round 5
// 206.932 us; speedup vs baseline: 1.4600x; 1.4600x over previous
//
#include <hip/hip_runtime.h>

// ---------------------------------------------------------------------------
// CausalSelfAttention (B=1, T=2048, DIM=1024, H=8, hd=128, scale=0.12)
// R5: attention q-tile=128 (2 q-sets/wave, K/V frags reused), K+V both in
//     LDS via async global_load_lds with XOR swizzle (R4-proven, 0 conflicts),
//     S^T = K*Q^T then PV via mfma_16x16x16 (P already in B-layout),
//     2-barrier pipelined staging (K single-buf, V double-buf, 48KB LDS).
//     GEMMs: BM=64 BK=64 tiles -> 768/512 blocks.
// MFMA layouts (m89/m91): x32: A[m=ln][k=quad*8+j]; x16: A[m=ln][k=quad*4+j];
//   B mirrors with n=ln; C/D: row=quad*4+reg, col=ln (quad=lane>>4)
// ---------------------------------------------------------------------------

typedef __attribute__((ext_vector_type(8))) short short8;      // 8 bf16
typedef __attribute__((ext_vector_type(4))) short short4b;     // 4 bf16
typedef __attribute__((ext_vector_type(4))) float fx4;         // MFMA acc
typedef __attribute__((ext_vector_type(8))) unsigned short ushort8;
typedef __attribute__((ext_vector_type(4))) unsigned short ushort4v;
typedef __attribute__((ext_vector_type(2))) unsigned short ushort2v;
typedef __attribute__((ext_vector_type(4))) float float4v;

#define T_SEQ 2048
#define NH 8
#define HD 128

__device__ __forceinline__ unsigned short f2bf(float f) {
  union { float f; unsigned u; } v; v.f = f;
  unsigned u = v.u;
  u += 0x7fffu + ((u >> 16) & 1u);        // RNE, finite inputs only
  return (unsigned short)(u >> 16);
}
__device__ __forceinline__ short bf_t(float f) {  // truncate (fast)
  union { float f; unsigned u; } v; v.f = f;
  return (short)(v.u >> 16);
}
__device__ __forceinline__ float bf2f(unsigned short h) {
  union { unsigned u; float f; } v; v.u = ((unsigned)h) << 16;
  return v.f;
}

// async global->LDS, 16B/lane; LDS dest = wave-uniform base + lane*16
typedef __attribute__((address_space(1))) unsigned int glb_u32;
typedef __attribute__((address_space(3))) unsigned int lds_u32;
__device__ __forceinline__ void gl_lds16(const unsigned short* g, unsigned short* l) {
  __builtin_amdgcn_global_load_lds((const glb_u32*)g, (lds_u32*)l, 16, 0, 0);
}

// ---------------------------------------------------------------------------
// Kernel 0: cast x (2M), qkv_w (3M), c_proj_w (1M) fp32 -> bf16 contiguous.
// ---------------------------------------------------------------------------
__global__ __launch_bounds__(256) void cast3_kernel(
    const float* __restrict__ x, const float* __restrict__ w1,
    const float* __restrict__ w2, unsigned short* __restrict__ o) {
  long q = (long)blockIdx.x * 256 + threadIdx.x;   // quad index
  const float* src;
  if (q < 524288)        src = x  + 4 * q;
  else if (q < 1310720)  src = w1 + 4 * (q - 524288);
  else                   src = w2 + 4 * (q - 1310720);
  float4v v = *(const float4v*)src;
  ushort4v r;
  r[0] = f2bf(v[0]); r[1] = f2bf(v[1]); r[2] = f2bf(v[2]); r[3] = f2bf(v[3]);
  *(ushort4v*)(o + 4 * q) = r;
}

// ---------------------------------------------------------------------------
// GEMM (BT): C[M,N] = A[M,K]*B[N,K]^T, bf16 in / fp32 acc. Tile BM x BN,
// BK=64, 4 waves (2x2, wave tile BM/2 x BN/2). global_load_lds width=16;
// LDS rows of 64 shorts (8 chunks); chunk c of row m stored at c ^ (m&7).
// ---------------------------------------------------------------------------
template <bool OUT_BF16, int BM, int BN>
__global__ __launch_bounds__(256) void gemm_bt3(
    const unsigned short* __restrict__ A, const unsigned short* __restrict__ B,
    void* __restrict__ Cp, int M, int N, int K) {
  constexpr int MT = BM / 32;                 // 16-row m-tiles per wave
  constexpr int NT = BN / 32;
  constexpr int ASEG = BM / 8;                // 1KB segments for A
  constexpr int NLOAD = (BM + BN) / 32;       // segments per wave
  __shared__ unsigned short a_sh[BM * 64];
  __shared__ unsigned short b_sh[BN * 64];
  const int tid = threadIdx.x;
  const int wave = tid >> 6, lane = tid & 63;
  const int ln = lane & 15, quad = lane >> 4;
  const int wm = wave & 1, wn = wave >> 1;
  const long arow0 = (long)blockIdx.y * BM;
  const long brow0 = (long)blockIdx.x * BN;

  const unsigned short* gsrc[NLOAD];
  unsigned short* ldst[NLOAD];
  for (int i = 0; i < NLOAD; ++i) {
    int s = wave * NLOAD + i;
    int isB = s >= ASEG;
    int srel = isB ? s - ASEG : s;
    int li = srel * 64 + lane;                // 16B chunk index in region
    int row = li >> 3, posc = li & 7;
    int c = posc ^ (row & 7);
    gsrc[i] = (isB ? B + brow0 * (long)K : A + arow0 * (long)K)
              + (long)row * K + c * 8;
    ldst[i] = (isB ? b_sh : a_sh) + srel * 512;
  }

  fx4 acc[MT][NT] = {};
  for (int k0 = 0; k0 < K; k0 += 64) {
    __syncthreads();
    for (int i = 0; i < NLOAD; ++i)
      gl_lds16(gsrc[i] + k0, ldst[i]);
    __syncthreads();
    short8 af[2][MT], bfr[2][NT];
    for (int kq = 0; kq < 2; ++kq) {
      for (int mt = 0; mt < MT; ++mt) {
        int m = wm * (BM / 2) + mt * 16 + ln;
        int pos = (kq * 4 + quad) ^ (m & 7);
        af[kq][mt] = *(const short8*)&a_sh[m * 64 + pos * 8];
      }
      for (int nt = 0; nt < NT; ++nt) {
        int n = wn * (BN / 2) + nt * 16 + ln;
        int pos = (kq * 4 + quad) ^ (n & 7);
        bfr[kq][nt] = *(const short8*)&b_sh[n * 64 + pos * 8];
      }
    }
    for (int kq = 0; kq < 2; ++kq)
      for (int mt = 0; mt < MT; ++mt)
        for (int nt = 0; nt < NT; ++nt)
          acc[mt][nt] = __builtin_amdgcn_mfma_f32_16x16x32_bf16(
              af[kq][mt], bfr[kq][nt], acc[mt][nt], 0, 0, 0);
  }
  for (int mt = 0; mt < MT; ++mt)
    for (int nt = 0; nt < NT; ++nt)
      for (int r = 0; r < 4; ++r) {
        long row = arow0 + wm * (BM / 2) + mt * 16 + quad * 4 + r;
        long col = brow0 + wn * (BN / 2) + nt * 16 + ln;
        float v = acc[mt][nt][r];
        if constexpr (OUT_BF16)
          ((unsigned short*)Cp)[row * N + col] = f2bf(v);
        else
          ((float*)Cp)[row * N + col] = v;
      }
}

// ---------------------------------------------------------------------------
// Kernel 2a: per-head RMSNorm + rotary for q,k. qhat/khat: [h][t][d] bf16.
// ---------------------------------------------------------------------------
__global__ __launch_bounds__(256) void qk_norm_rope(
    const unsigned short* __restrict__ qkv, unsigned short* __restrict__ qh,
    unsigned short* __restrict__ kh) {
  const int t = blockIdx.x;
  const int tid = threadIdx.x;
  const int h = tid >> 5, c = tid & 31;
  float cv[2], sv[2];
  for (int u = 0; u < 2; ++u) {
    int dd = 2 * c + u;
    if (dd < 32) {
      float ang = exp2f(-10.0f * (float)dd / 31.0f);  // (1/1024)^(dd/31)
      float th = (float)t * ang;
      sv[u] = __sinf(th); cv[u] = __cosf(th);
    } else { sv[u] = 0.f; cv[u] = 1.f; }
  }
  for (int which = 0; which < 2; ++which) {           // 0 = q, 1 = k
    const unsigned short* src = qkv + (long)t * 3072 + which * 1024 + h * 128;
    ushort2v aa = *(const ushort2v*)(src + 2 * c);
    ushort2v bb = *(const ushort2v*)(src + 64 + 2 * c);
    float x1[2] = { bf2f(aa[0]), bf2f(aa[1]) };
    float x2[2] = { bf2f(bb[0]), bf2f(bb[1]) };
    float ss = x1[0]*x1[0] + x1[1]*x1[1] + x2[0]*x2[0] + x2[1]*x2[1];
    for (int off = 1; off < 32; off <<= 1) ss += __shfl_xor(ss, off);
    float rn = rsqrtf(ss * (1.0f / 128.0f) + 1.1920929e-7f);
    ushort2v o1, o2;
    for (int u = 0; u < 2; ++u) {
      float y1 = ( x1[u] * cv[u] + x2[u] * sv[u]) * rn;
      float y2 = (-x1[u] * sv[u] + x2[u] * cv[u]) * rn;
      o1[u] = f2bf(y1); o2[u] = f2bf(y2);
    }
    unsigned short* dst = (which ? kh : qh) + ((long)h * T_SEQ + t) * 128;
    *(ushort2v*)(dst + 2 * c) = o1;
    *(ushort2v*)(dst + 64 + 2 * c) = o2;
  }
}

// ---------------------------------------------------------------------------
// Kernel 2b: v = l0*v + l1*ve, transpose to vt[h][d][t'] bf16 where within
// each 64-t tile positions are kt-interleaved: p(kv) with kv=(kt[1:0],q4,j):
// p = kt1*32 + q4*8 + kt0*4 + j. A b128 read at p-offset kh2*32+quad*8 then
// yields kt=2*kh2 (j0..3) and kt=2*kh2+1 (j4..7) A-frags for 16x16x16 PV.
// ---------------------------------------------------------------------------
__global__ __launch_bounds__(256) void v_combine_t(
    const unsigned short* __restrict__ qkv, const float* __restrict__ ve,
    const float* __restrict__ lambdas, unsigned short* __restrict__ vt) {
  __shared__ unsigned short lt[128 * 72];
  const int tt = blockIdx.x, h = blockIdx.y;
  const int tid = threadIdx.x;
  const float l0 = lambdas[0], l1 = lambdas[1];
  const int r = tid >> 2, cb = (tid & 3) * 32;
  const unsigned short* vs = qkv + (long)(tt * 64 + r) * 3072 + 2048 + h * 128 + cb;
  const float* es = ve + (long)(tt * 64 + r) * 1024 + h * 128 + cb;
  ushort8 vv[4];
  for (int q = 0; q < 4; ++q) vv[q] = *(const ushort8*)(vs + 8 * q);
  float4v ee[8];
  for (int q = 0; q < 8; ++q) ee[q] = *(const float4v*)(es + 4 * q);
  for (int j = 0; j < 32; ++j) {
    float v = bf2f(vv[j >> 3][j & 7]) * l0 + ee[j >> 2][j & 3] * l1;
    lt[(cb + j) * 72 + r] = f2bf(v);
  }
  __syncthreads();
  const int d = tid >> 1, half = tid & 1;
  unsigned short* dst = vt + ((long)h * HD + d) * T_SEQ + tt * 64 + half * 32;
  const unsigned short* srcl = &lt[d * 72];
  for (int g = 0; g < 8; ++g) {
    int p0 = half * 32 + g * 4;
    int kv0 = ((p0 >> 5) & 1) * 32 + ((p0 >> 2) & 1) * 16 + ((p0 >> 3) & 3) * 4;
    *(ushort4v*)(dst + g * 4) = *(const ushort4v*)(srcl + kv0);
  }
}

// ---------------------------------------------------------------------------
// Kernel 3a: chunked flash attention partials (q-tile 128, 2 q-sets/wave).
// Grid (qt=16, h=8, ch=8); chunk covers 64-kv tiles [4ch, min(4ch+3, 2qt+1)].
// Per jt: [top barrier] S^T = K*Q^T (K frags reused across 2 q-sets)
//         [mid barrier] issue async K(jt+1)->kbuf, V(jt+1)->vbuf[cur^1]
//         softmax (fixed-max), PV via mfma_16x16x16 (V frag reused x4).
// K LDS [64][128] chunks swizzled c^(row&15); V LDS [128][64] interleaved-kv
// rows, chunks swizzled c^(row&7). Partials: per head, qt-tile qt has
// c(qt)=(qt>>1)+1 chunks at base(qt)=qt+((qt-1)^2)/4; pp=h*72+base+ch.
// Yp bf16 [pp][128 q][128 d], lp fp32 [pp][128].
// ---------------------------------------------------------------------------
#define ATT_C1 0.17312340490667562f   // 0.12 * log2(e)
#define ATT_C2 23.083120654223415f    // 16   * log2(e)

__global__ __launch_bounds__(256, 3) void attn_part(
    const unsigned short* __restrict__ qh, const unsigned short* __restrict__ kh,
    const unsigned short* __restrict__ vt, unsigned short* __restrict__ Yp,
    float* __restrict__ lp) {
  __shared__ unsigned short kbuf[8192];       // 16KB: K tile [64][128]
  __shared__ unsigned short vbuf[2][8192];    // 2x16KB: V^T tile [128][64]
  const int tid = threadIdx.x;
  const int wave = tid >> 6, lane = tid & 63;
  const int ln = lane & 15, quad = lane >> 4;
  const int qt = blockIdx.x, h = blockIdx.y, ch = blockIdx.z;
  const int jmax = 2 * qt + 1;
  const int j0 = ch * 4;
  if (j0 > jmax) return;                      // uniform per block
  const int j1 = min(j0 + 3, jmax);

  int qg[2];
  short8 qf[2][4];
  for (int s = 0; s < 2; ++s) {
    qg[s] = qt * 128 + wave * 32 + s * 16 + ln;
    const unsigned short* qbase = qh + ((long)h * T_SEQ + qg[s]) * 128;
    for (int kc = 0; kc < 4; ++kc)
      qf[s][kc] = *(const short8*)(qbase + kc * 32 + quad * 8);
  }
  fx4 accy[2][8] = {};
  float l_loc[2] = {0.f, 0.f};

  // staging descriptors (4 K segs + 4 V segs per wave)
  const unsigned short* kg[4]; unsigned short* kl[4];
  const unsigned short* vg[4]; unsigned short* vl[4];
  for (int i = 0; i < 4; ++i) {
    int s = wave * 4 + i;
    { int li = s * 64 + lane; int row = li >> 4, posc = li & 15;
      int c = posc ^ (row & 15);
      kg[i] = kh + ((long)h * T_SEQ + row) * 128 + c * 8;
      kl[i] = &kbuf[s * 512]; }
    { int li = s * 64 + lane; int row = li >> 3, posc = li & 7;
      int c = posc ^ (row & 7);
      vg[i] = vt + ((long)h * HD + row) * T_SEQ + c * 8;
      vl[i] = &vbuf[0][s * 512]; }
  }
  // initial stage: K(j0), V(j0) -> vbuf[0]
  for (int i = 0; i < 4; ++i) gl_lds16(kg[i] + (long)j0 * 8192, kl[i]);
  for (int i = 0; i < 4; ++i) gl_lds16(vg[i] + (long)j0 * 64, vl[i]);

  int cur = 0;
  for (int jt = j0; jt <= j1; ++jt, cur ^= 1) {
    __syncthreads();                          // drains async; publishes K,V
    // ---- S^T phase: read kbuf only ----
    fx4 s4[2][4];
    for (int kt = 0; kt < 4; ++kt) {
      s4[0][kt] = fx4{0.f, 0.f, 0.f, 0.f};
      s4[1][kt] = fx4{0.f, 0.f, 0.f, 0.f};
      for (int kc = 0; kc < 4; ++kc) {
        int pos = (kc * 4 + quad) ^ ln;
        short8 kf = *(const short8*)&kbuf[(kt * 16 + ln) * 128 + pos * 8];
        s4[0][kt] = __builtin_amdgcn_mfma_f32_16x16x32_bf16(kf, qf[0][kc], s4[0][kt], 0, 0, 0);
        s4[1][kt] = __builtin_amdgcn_mfma_f32_16x16x32_bf16(kf, qf[1][kc], s4[1][kt], 0, 0, 0);
      }
    }
    __syncthreads();                          // all K reads done
    if (jt < j1) {                            // stage next tile (async)
      for (int i = 0; i < 4; ++i) gl_lds16(kg[i] + (long)(jt + 1) * 8192, kl[i]);
      for (int i = 0; i < 4; ++i) gl_lds16(vg[i] + (long)(jt + 1) * 64, vl[i] + (cur ^ 1) * 8192);
    }
    // ---- softmax (fixed max), pack P^T B-frags ----
    short4b pb[2][4];
    for (int s = 0; s < 2; ++s)
      for (int kt = 0; kt < 4; ++kt) {
        int kvb = jt * 64 + kt * 16 + quad * 4;
        float p[4];
        for (int r = 0; r < 4; ++r) {
          float pv = exp2f(fmaf(s4[s][kt][r], ATT_C1, -ATT_C2));
          p[r] = pv;
        }
        if (jt * 64 + kt * 16 + 15 > qt * 128 + wave * 32 + s * 16) {
          for (int r = 0; r < 4; ++r) if (kvb + r > qg[s]) p[r] = 0.f;
        }
        l_loc[s] += (p[0] + p[1]) + (p[2] + p[3]);
        pb[s][kt] = short4b{ bf_t(p[0]), bf_t(p[1]), bf_t(p[2]), bf_t(p[3]) };
      }
    // ---- PV phase: read vbuf[cur] ----
    const unsigned short* vb_ = &vbuf[cur][0];
    for (int kh2 = 0; kh2 < 2; ++kh2) {
      for (int dt = 0; dt < 8; ++dt) {
        int row = dt * 16 + ln;
        int pos = (kh2 * 4 + quad) ^ (ln & 7);
        short8 va = *(const short8*)&vb_[row * 64 + pos * 8];
        short4b va0 = { va[0], va[1], va[2], va[3] };
        short4b va1 = { va[4], va[5], va[6], va[7] };
        for (int s = 0; s < 2; ++s) {
          accy[s][dt] = __builtin_amdgcn_mfma_f32_16x16x16bf16_1k(
              va0, pb[s][kh2 * 2], accy[s][dt], 0, 0, 0);
          accy[s][dt] = __builtin_amdgcn_mfma_f32_16x16x16bf16_1k(
              va1, pb[s][kh2 * 2 + 1], accy[s][dt], 0, 0, 0);
        }
      }
    }
  }

  int cbase = qt + ((qt - 1) * (qt - 1)) / 4;     // qt=0 -> 0
  const long pp = (long)(h * 72 + cbase + ch);
  for (int s = 0; s < 2; ++s) {
    float l = l_loc[s];
    l += __shfl_xor(l, 16);
    l += __shfl_xor(l, 32);
    int q = wave * 32 + s * 16 + ln;
    if (quad == 0) lp[pp * 128 + q] = l;
    unsigned short* yb = Yp + pp * 16384 + (long)q * 128;
    for (int dt = 0; dt < 8; ++dt) {
      ushort4v o;
      for (int r = 0; r < 4; ++r) o[r] = f2bf(accy[s][dt][r]);
      *(ushort4v*)(yb + dt * 16 + quad * 4) = o;
    }
  }
}

// ---------------------------------------------------------------------------
// Kernel 3b: combine partials: Y = (sum_c Yp)/(sum_c lp) -> ybf [t][h*128+d].
// Grid (32, 8): blockIdx.x = 64-row half-tiles (qt = bx>>1, sub = bx&1).
// ---------------------------------------------------------------------------
__global__ __launch_bounds__(256) void attn_combine(
    const unsigned short* __restrict__ Yp, const float* __restrict__ lp,
    unsigned short* __restrict__ y) {
  const int bx = blockIdx.x, h = blockIdx.y;
  const int qt = bx >> 1, sub = bx & 1;
  const int tid = threadIdx.x;
  const int row = sub * 64 + (tid >> 2), cb = (tid & 3) * 32;
  const int nc = (qt >> 1) + 1;
  const int cbase = qt + ((qt - 1) * (qt - 1)) / 4;
  float acc[32];
  for (int j = 0; j < 32; ++j) acc[j] = 0.f;
  float ltot = 0.f;
  for (int c = 0; c < nc; ++c) {
    long pp = (long)(h * 72 + cbase + c);
    const unsigned short* ys = Yp + pp * 16384 + (long)row * 128 + cb;
    ltot += lp[pp * 128 + row];
    for (int q8 = 0; q8 < 4; ++q8) {
      ushort8 v = *(const ushort8*)(ys + q8 * 8);
      for (int j = 0; j < 8; ++j) acc[q8 * 8 + j] += bf2f(v[j]);
    }
  }
  float inv = 1.f / ltot;
  unsigned short* dst = y + (long)(qt * 128 + row) * 1024 + h * 128 + cb;
  for (int q8 = 0; q8 < 4; ++q8) {
    ushort8 o;
    for (int j = 0; j < 8; ++j) o[j] = f2bf(acc[q8 * 8 + j] * inv);
    *(ushort8*)(dst + q8 * 8) = o;
  }
}

// ---------------------------------------------------------------------------
// Workspace layout (bytes), ~42 MB. Attention partials reuse dead regions:
//   0        : qkv_bf (12MB)  | attn: Yp bf16 8*72*32KB = 18.87MB (0..18.87M)
//   12582912 : x_bf   (4MB)   | attn: lp fp32 @18874368 (295KB)
//   16777216 : wqkv   (6MB)
//   23068672 : wproj  (2MB, live until GEMM2)
//   25165824 : qhat [8][2048][128] (4MB)
//   29360128 : khat (4MB)
//   33554432 : vt   [8][128][2048] interleaved (4MB)
//   37748736 : ybf  [2048][1024] (4MB)
// ---------------------------------------------------------------------------
extern "C" void kernel_launch(void* const* d_in, const int* in_sizes, int n_in,
                              void* d_out, int out_size, void* d_ws, size_t ws_size,
                              hipStream_t stream) {
  const float* x       = (const float*)d_in[0];
  const float* ve      = (const float*)d_in[1];
  const float* qkv_w   = (const float*)d_in[2];
  const float* lambdas = (const float*)d_in[3];
  const float* c_proj  = (const float*)d_in[4];
  char* ws = (char*)d_ws;
  unsigned short* qkv_bf = (unsigned short*)(ws);
  unsigned short* x_bf   = (unsigned short*)(ws + 12582912);
  unsigned short* wqkv   = (unsigned short*)(ws + 16777216);
  unsigned short* wproj  = (unsigned short*)(ws + 23068672);
  unsigned short* qhat   = (unsigned short*)(ws + 25165824);
  unsigned short* khat   = (unsigned short*)(ws + 29360128);
  unsigned short* vtb    = (unsigned short*)(ws + 33554432);
  unsigned short* ybf    = (unsigned short*)(ws + 37748736);
  unsigned short* Yp     = (unsigned short*)(ws);              // reuse, 18.9MB
  float*          lpart  = (float*)(ws + 18874368);            // reuse, 295KB
  float* out = (float*)d_out;

  cast3_kernel<<<6144, 256, 0, stream>>>(x, qkv_w, c_proj, x_bf);
  gemm_bt3<true, 64, 128><<<dim3(24, 32), 256, 0, stream>>>(x_bf, wqkv, qkv_bf, 2048, 3072, 1024);
  qk_norm_rope<<<2048, 256, 0, stream>>>(qkv_bf, qhat, khat);
  v_combine_t<<<dim3(32, 8), 256, 0, stream>>>(qkv_bf, ve, lambdas, vtb);
  attn_part<<<dim3(16, 8, 8), 256, 0, stream>>>(qhat, khat, vtb, Yp, lpart);
  attn_combine<<<dim3(32, 8), 256, 0, stream>>>(Yp, lpart, ybf);
  gemm_bt3<false, 64, 64><<<dim3(16, 32), 256, 0, stream>>>(ybf, wproj, out, 2048, 1024, 1024);
}

// Round 6
// 194.631 us; speedup vs baseline: 1.5523x; 1.0632x over previous
//
#include <hip/hip_runtime.h>

// ---------------------------------------------------------------------------
// CausalSelfAttention (B=1, T=2048, DIM=1024, H=8, hd=128, scale=0.12)
// R6: single-barrier, full-iteration-prefetch pipelines everywhere:
//   - attn: K+V double-buffered LDS; loads for jt+1 issued right after the
//     one barrier, before S^T/softmax/PV compute of jt (full-iter overlap).
//   - GEMM: same structure (dbuf, 1 barrier/BK-iter).
//   - prep_qkv: fused RMSNorm+rope (q,k) + V lambda-combine/transpose.
// MFMA layouts (m89/m91): x32: A[m=ln][k=quad*8+j]; x16: A[m=ln][k=quad*4+j];
//   B mirrors with n=ln; C/D: row=quad*4+reg, col=ln (quad=lane>>4)
// ---------------------------------------------------------------------------

typedef __attribute__((ext_vector_type(8))) short short8;      // 8 bf16
typedef __attribute__((ext_vector_type(4))) short short4b;     // 4 bf16
typedef __attribute__((ext_vector_type(4))) float fx4;         // MFMA acc
typedef __attribute__((ext_vector_type(8))) unsigned short ushort8;
typedef __attribute__((ext_vector_type(4))) unsigned short ushort4v;
typedef __attribute__((ext_vector_type(2))) unsigned short ushort2v;
typedef __attribute__((ext_vector_type(4))) float float4v;

#define T_SEQ 2048
#define NH 8
#define HD 128

__device__ __forceinline__ unsigned short f2bf(float f) {
  union { float f; unsigned u; } v; v.f = f;
  unsigned u = v.u;
  u += 0x7fffu + ((u >> 16) & 1u);        // RNE, finite inputs only
  return (unsigned short)(u >> 16);
}
__device__ __forceinline__ short bf_t(float f) {  // truncate (fast)
  union { float f; unsigned u; } v; v.f = f;
  return (short)(v.u >> 16);
}
__device__ __forceinline__ float bf2f(unsigned short h) {
  union { unsigned u; float f; } v; v.u = ((unsigned)h) << 16;
  return v.f;
}

// async global->LDS, 16B/lane; LDS dest = wave-uniform base + lane*16
typedef __attribute__((address_space(1))) unsigned int glb_u32;
typedef __attribute__((address_space(3))) unsigned int lds_u32;
__device__ __forceinline__ void gl_lds16(const unsigned short* g, unsigned short* l) {
  __builtin_amdgcn_global_load_lds((const glb_u32*)g, (lds_u32*)l, 16, 0, 0);
}

// ---------------------------------------------------------------------------
// Kernel 0: cast x (2M), qkv_w (3M), c_proj_w (1M) fp32 -> bf16 contiguous.
// ---------------------------------------------------------------------------
__global__ __launch_bounds__(256) void cast3_kernel(
    const float* __restrict__ x, const float* __restrict__ w1,
    const float* __restrict__ w2, unsigned short* __restrict__ o) {
  long q = (long)blockIdx.x * 256 + threadIdx.x;   // quad index
  const float* src;
  if (q < 524288)        src = x  + 4 * q;
  else if (q < 1310720)  src = w1 + 4 * (q - 524288);
  else                   src = w2 + 4 * (q - 1310720);
  float4v v = *(const float4v*)src;
  ushort4v r;
  r[0] = f2bf(v[0]); r[1] = f2bf(v[1]); r[2] = f2bf(v[2]); r[3] = f2bf(v[3]);
  *(ushort4v*)(o + 4 * q) = r;
}

// ---------------------------------------------------------------------------
// GEMM (BT): C[M,N] = A[M,K]*B[N,K]^T, bf16 in / fp32 acc. Tile BM x BN,
// BK=64, 4 waves (2x2, wave tile BM/2 x BN/2). Double-buffered LDS,
// ONE barrier per K-iter; next-iter global_load_lds issued right after the
// barrier (full-iteration prefetch). 16B chunk c of row m at pos c^(m&7).
// ---------------------------------------------------------------------------
template <bool OUT_BF16, int BM, int BN>
__global__ __launch_bounds__(256) void gemm_bt4(
    const unsigned short* __restrict__ A, const unsigned short* __restrict__ B,
    void* __restrict__ Cp, int M, int N, int K) {
  constexpr int MT = BM / 32;
  constexpr int NT = BN / 32;
  constexpr int ASEG = BM / 8;                // 512-short segments in A region
  constexpr int NLOAD = (BM + BN) / 32;       // segments per wave
  __shared__ unsigned short a_sh[2][BM * 64];
  __shared__ unsigned short b_sh[2][BN * 64];
  const int tid = threadIdx.x;
  const int wave = tid >> 6, lane = tid & 63;
  const int ln = lane & 15, quad = lane >> 4;
  const int wm = wave & 1, wn = wave >> 1;
  const long arow0 = (long)blockIdx.y * BM;
  const long brow0 = (long)blockIdx.x * BN;

  const unsigned short* gsrc[NLOAD];
  unsigned short* ldst[NLOAD];
  int bstr[NLOAD];
  for (int i = 0; i < NLOAD; ++i) {
    int s = wave * NLOAD + i;
    int isB = s >= ASEG;
    int srel = isB ? s - ASEG : s;
    int li = srel * 64 + lane;                // 16B chunk index in region
    int row = li >> 3, posc = li & 7;
    int c = posc ^ (row & 7);
    gsrc[i] = (isB ? B + brow0 * (long)K : A + arow0 * (long)K)
              + (long)row * K + c * 8;
    ldst[i] = (isB ? &b_sh[0][0] : &a_sh[0][0]) + srel * 512;
    bstr[i] = isB ? BN * 64 : BM * 64;
  }
  // prologue: stage k0=0 into buffer 0
  for (int i = 0; i < NLOAD; ++i) gl_lds16(gsrc[i], ldst[i]);

  fx4 acc[MT][NT] = {};
  int cur = 0;
  for (int k0 = 0; k0 < K; k0 += 64, cur ^= 1) {
    __syncthreads();                          // drains async; publishes cur
    if (k0 + 64 < K)                          // prefetch next into cur^1
      for (int i = 0; i < NLOAD; ++i)
        gl_lds16(gsrc[i] + k0 + 64, ldst[i] + (cur ^ 1) * bstr[i]);
    const unsigned short* ash = &a_sh[cur][0];
    const unsigned short* bsh = &b_sh[cur][0];
    short8 af[2][MT], bfr[2][NT];
    for (int kq = 0; kq < 2; ++kq) {
      for (int mt = 0; mt < MT; ++mt) {
        int m = wm * (BM / 2) + mt * 16 + ln;
        int pos = (kq * 4 + quad) ^ (m & 7);
        af[kq][mt] = *(const short8*)&ash[m * 64 + pos * 8];
      }
      for (int nt = 0; nt < NT; ++nt) {
        int n = wn * (BN / 2) + nt * 16 + ln;
        int pos = (kq * 4 + quad) ^ (n & 7);
        bfr[kq][nt] = *(const short8*)&bsh[n * 64 + pos * 8];
      }
    }
    for (int kq = 0; kq < 2; ++kq)
      for (int mt = 0; mt < MT; ++mt)
        for (int nt = 0; nt < NT; ++nt)
          acc[mt][nt] = __builtin_amdgcn_mfma_f32_16x16x32_bf16(
              af[kq][mt], bfr[kq][nt], acc[mt][nt], 0, 0, 0);
  }
  for (int mt = 0; mt < MT; ++mt)
    for (int nt = 0; nt < NT; ++nt)
      for (int r = 0; r < 4; ++r) {
        long row = arow0 + wm * (BM / 2) + mt * 16 + quad * 4 + r;
        long col = brow0 + wn * (BN / 2) + nt * 16 + ln;
        float v = acc[mt][nt][r];
        if constexpr (OUT_BF16)
          ((unsigned short*)Cp)[row * N + col] = f2bf(v);
        else
          ((float*)Cp)[row * N + col] = v;
      }
}

// ---------------------------------------------------------------------------
// Kernel 2 (fused): per-head RMSNorm+rope for q,k  AND  v-combine+transpose.
// Grid (tt=32, h=8). Part A: rows tt*64..+63 of head h for q and k.
// Part B: v = l0*v + l1*ve -> vt[h][d][t'] with kt-interleaved positions
// (p = kt1*32 + q4*8 + kt0*4 + j) for direct 16x16x16 PV A-frag b128 reads.
// ---------------------------------------------------------------------------
__global__ __launch_bounds__(256) void prep_qkv(
    const unsigned short* __restrict__ qkv, const float* __restrict__ ve,
    const float* __restrict__ lambdas, unsigned short* __restrict__ qh,
    unsigned short* __restrict__ kh, unsigned short* __restrict__ vt) {
  __shared__ unsigned short lt[128 * 72];
  const int tt = blockIdx.x, h = blockIdx.y;
  const int tid = threadIdx.x;

  // ---- Part A: norm + rope ----
  {
    const int r2 = tid >> 5, c = tid & 31;
    float ang[2];
    for (int u = 0; u < 2; ++u) {
      int dd = 2 * c + u;
      ang[u] = (dd < 32) ? exp2f(-10.0f * (float)dd / 31.0f) : 0.0f;
    }
    for (int rr = 0; rr < 8; ++rr) {
      int t = tt * 64 + rr * 8 + r2;
      float cv[2], sv[2];
      for (int u = 0; u < 2; ++u) {
        float th = (float)t * ang[u];
        sv[u] = __sinf(th); cv[u] = __cosf(th);
      }
      for (int which = 0; which < 2; ++which) {       // 0 = q, 1 = k
        const unsigned short* src = qkv + (long)t * 3072 + which * 1024 + h * 128;
        ushort2v aa = *(const ushort2v*)(src + 2 * c);
        ushort2v bb = *(const ushort2v*)(src + 64 + 2 * c);
        float x1[2] = { bf2f(aa[0]), bf2f(aa[1]) };
        float x2[2] = { bf2f(bb[0]), bf2f(bb[1]) };
        float ss = x1[0]*x1[0] + x1[1]*x1[1] + x2[0]*x2[0] + x2[1]*x2[1];
        for (int off = 1; off < 32; off <<= 1) ss += __shfl_xor(ss, off);
        float rn = rsqrtf(ss * (1.0f / 128.0f) + 1.1920929e-7f);
        ushort2v o1, o2;
        for (int u = 0; u < 2; ++u) {
          float y1 = ( x1[u] * cv[u] + x2[u] * sv[u]) * rn;
          float y2 = (-x1[u] * sv[u] + x2[u] * cv[u]) * rn;
          o1[u] = f2bf(y1); o2[u] = f2bf(y2);
        }
        unsigned short* dst = (which ? kh : qh) + ((long)h * T_SEQ + t) * 128;
        *(ushort2v*)(dst + 2 * c) = o1;
        *(ushort2v*)(dst + 64 + 2 * c) = o2;
      }
    }
  }

  // ---- Part B: v combine + interleaved transpose ----
  {
    const float l0 = lambdas[0], l1 = lambdas[1];
    const int r = tid >> 2, cb = (tid & 3) * 32;
    const unsigned short* vs = qkv + (long)(tt * 64 + r) * 3072 + 2048 + h * 128 + cb;
    const float* es = ve + (long)(tt * 64 + r) * 1024 + h * 128 + cb;
    ushort8 vv[4];
    for (int q = 0; q < 4; ++q) vv[q] = *(const ushort8*)(vs + 8 * q);
    float4v ee[8];
    for (int q = 0; q < 8; ++q) ee[q] = *(const float4v*)(es + 4 * q);
    for (int j = 0; j < 32; ++j) {
      float v = bf2f(vv[j >> 3][j & 7]) * l0 + ee[j >> 2][j & 3] * l1;
      lt[(cb + j) * 72 + r] = f2bf(v);
    }
    __syncthreads();
    const int d = tid >> 1, half = tid & 1;
    unsigned short* dst = vt + ((long)h * HD + d) * T_SEQ + tt * 64 + half * 32;
    const unsigned short* srcl = &lt[d * 72];
    for (int g = 0; g < 8; ++g) {
      int p0 = half * 32 + g * 4;
      int kv0 = ((p0 >> 5) & 1) * 32 + ((p0 >> 2) & 1) * 16 + ((p0 >> 3) & 3) * 4;
      *(ushort4v*)(dst + g * 4) = *(const ushort4v*)(srcl + kv0);
    }
  }
}

// ---------------------------------------------------------------------------
// Kernel 3a: chunked flash attention partials (q-tile 128, 2 q-sets/wave).
// Grid (qt=16, h=8, ch=8); chunk covers 64-kv tiles [4ch, min(4ch+3, 2qt+1)].
// R6 pipeline: K and V double-buffered; ONE barrier per jt; async loads for
// jt+1 issued immediately after the barrier -> full-iteration overlap.
// S^T = K*Q^T (16x16x32); fixed-max softmax; PV via mfma_16x16x16 (P in
// B-layout from C-layout, zero data movement). XOR-swizzled staging
// (0 bank conflicts, R4/R5-verified). Partials: pp=h*72+cbase(qt)+ch;
// Yp bf16 [pp][128 q][128 d], lp fp32 [pp][128].
// ---------------------------------------------------------------------------
#define ATT_C1 0.17312340490667562f   // 0.12 * log2(e)
#define ATT_C2 23.083120654223415f    // 16   * log2(e)

__global__ __launch_bounds__(256, 2) void attn_part(
    const unsigned short* __restrict__ qh, const unsigned short* __restrict__ kh,
    const unsigned short* __restrict__ vt, unsigned short* __restrict__ Yp,
    float* __restrict__ lp) {
  __shared__ unsigned short kbuf[2][8192];    // 2 x 16KB: K tile [64][128]
  __shared__ unsigned short vbuf[2][8192];    // 2 x 16KB: V^T tile [128][64]
  const int tid = threadIdx.x;
  const int wave = tid >> 6, lane = tid & 63;
  const int ln = lane & 15, quad = lane >> 4;
  const int qt = blockIdx.x, h = blockIdx.y, ch = blockIdx.z;
  const int jmax = 2 * qt + 1;
  const int j0 = ch * 4;
  if (j0 > jmax) return;                      // uniform per block
  const int j1 = min(j0 + 3, jmax);

  int qg[2];
  short8 qf[2][4];
  for (int s = 0; s < 2; ++s) {
    qg[s] = qt * 128 + wave * 32 + s * 16 + ln;
    const unsigned short* qbase = qh + ((long)h * T_SEQ + qg[s]) * 128;
    for (int kc = 0; kc < 4; ++kc)
      qf[s][kc] = *(const short8*)(qbase + kc * 32 + quad * 8);
  }
  fx4 accy[2][8] = {};
  float l_loc[2] = {0.f, 0.f};

  // staging descriptors (4 K segs + 4 V segs per wave)
  const unsigned short* kg[4]; unsigned short* kl[4];
  const unsigned short* vg[4]; unsigned short* vl[4];
  for (int i = 0; i < 4; ++i) {
    int s = wave * 4 + i;
    { int li = s * 64 + lane; int row = li >> 4, posc = li & 15;
      int c = posc ^ (row & 15);
      kg[i] = kh + ((long)h * T_SEQ + row) * 128 + c * 8;
      kl[i] = &kbuf[0][s * 512]; }
    { int li = s * 64 + lane; int row = li >> 3, posc = li & 7;
      int c = posc ^ (row & 7);
      vg[i] = vt + ((long)h * HD + row) * T_SEQ + c * 8;
      vl[i] = &vbuf[0][s * 512]; }
  }
  // prologue: stage K(j0), V(j0) -> buffer 0
  for (int i = 0; i < 4; ++i) gl_lds16(kg[i] + (long)j0 * 8192, kl[i]);
  for (int i = 0; i < 4; ++i) gl_lds16(vg[i] + (long)j0 * 64, vl[i]);

  int cur = 0;
  for (int jt = j0; jt <= j1; ++jt, cur ^= 1) {
    __syncthreads();                // drains async loads; publishes buf[cur],
                                    // and frees buf[cur^1] (jt-1 compute done)
    if (jt < j1) {                  // full-iteration prefetch into cur^1
      int nb = (cur ^ 1) * 8192;
      for (int i = 0; i < 4; ++i) gl_lds16(kg[i] + (long)(jt + 1) * 8192, kl[i] + nb);
      for (int i = 0; i < 4; ++i) gl_lds16(vg[i] + (long)(jt + 1) * 64, vl[i] + nb);
    }
    const unsigned short* kb_ = &kbuf[cur][0];
    // ---- S^T phase ----
    fx4 s4[2][4];
    for (int kt = 0; kt < 4; ++kt) {
      s4[0][kt] = fx4{0.f, 0.f, 0.f, 0.f};
      s4[1][kt] = fx4{0.f, 0.f, 0.f, 0.f};
      for (int kc = 0; kc < 4; ++kc) {
        int pos = (kc * 4 + quad) ^ ln;
        short8 kf = *(const short8*)&kb_[(kt * 16 + ln) * 128 + pos * 8];
        s4[0][kt] = __builtin_amdgcn_mfma_f32_16x16x32_bf16(kf, qf[0][kc], s4[0][kt], 0, 0, 0);
        s4[1][kt] = __builtin_amdgcn_mfma_f32_16x16x32_bf16(kf, qf[1][kc], s4[1][kt], 0, 0, 0);
      }
    }
    // ---- softmax (fixed max), pack P^T B-frags ----
    short4b pb[2][4];
    for (int s = 0; s < 2; ++s)
      for (int kt = 0; kt < 4; ++kt) {
        int kvb = jt * 64 + kt * 16 + quad * 4;
        float p[4];
        for (int r = 0; r < 4; ++r)
          p[r] = exp2f(fmaf(s4[s][kt][r], ATT_C1, -ATT_C2));
        if (jt * 64 + kt * 16 + 15 > qt * 128 + wave * 32 + s * 16) {
          for (int r = 0; r < 4; ++r) if (kvb + r > qg[s]) p[r] = 0.f;
        }
        l_loc[s] += (p[0] + p[1]) + (p[2] + p[3]);
        pb[s][kt] = short4b{ bf_t(p[0]), bf_t(p[1]), bf_t(p[2]), bf_t(p[3]) };
      }
    // ---- PV phase ----
    const unsigned short* vb_ = &vbuf[cur][0];
    for (int kh2 = 0; kh2 < 2; ++kh2) {
      for (int dt = 0; dt < 8; ++dt) {
        int row = dt * 16 + ln;
        int pos = (kh2 * 4 + quad) ^ (ln & 7);
        short8 va = *(const short8*)&vb_[row * 64 + pos * 8];
        short4b va0 = { va[0], va[1], va[2], va[3] };
        short4b va1 = { va[4], va[5], va[6], va[7] };
        for (int s = 0; s < 2; ++s) {
          accy[s][dt] = __builtin_amdgcn_mfma_f32_16x16x16bf16_1k(
              va0, pb[s][kh2 * 2], accy[s][dt], 0, 0, 0);
          accy[s][dt] = __builtin_amdgcn_mfma_f32_16x16x16bf16_1k(
              va1, pb[s][kh2 * 2 + 1], accy[s][dt], 0, 0, 0);
        }
      }
    }
  }

  int cbase = qt + ((qt - 1) * (qt - 1)) / 4;     // qt=0 -> 0
  const long pp = (long)(h * 72 + cbase + ch);
  for (int s = 0; s < 2; ++s) {
    float l = l_loc[s];
    l += __shfl_xor(l, 16);
    l += __shfl_xor(l, 32);
    int q = wave * 32 + s * 16 + ln;
    if (quad == 0) lp[pp * 128 + q] = l;
    unsigned short* yb = Yp + pp * 16384 + (long)q * 128;
    for (int dt = 0; dt < 8; ++dt) {
      ushort4v o;
      for (int r = 0; r < 4; ++r) o[r] = f2bf(accy[s][dt][r]);
      *(ushort4v*)(yb + dt * 16 + quad * 4) = o;
    }
  }
}

// ---------------------------------------------------------------------------
// Kernel 3b: combine partials: Y = (sum_c Yp)/(sum_c lp) -> ybf [t][h*128+d].
// Grid (32, 8): blockIdx.x = 64-row half-tiles (qt = bx>>1, sub = bx&1).
// ---------------------------------------------------------------------------
__global__ __launch_bounds__(256) void attn_combine(
    const unsigned short* __restrict__ Yp, const float* __restrict__ lp,
    unsigned short* __restrict__ y) {
  const int bx = blockIdx.x, h = blockIdx.y;
  const int qt = bx >> 1, sub = bx & 1;
  const int tid = threadIdx.x;
  const int row = sub * 64 + (tid >> 2), cb = (tid & 3) * 32;
  const int nc = (qt >> 1) + 1;
  const int cbase = qt + ((qt - 1) * (qt - 1)) / 4;
  float acc[32];
  for (int j = 0; j < 32; ++j) acc[j] = 0.f;
  float ltot = 0.f;
  for (int c = 0; c < nc; ++c) {
    long pp = (long)(h * 72 + cbase + c);
    const unsigned short* ys = Yp + pp * 16384 + (long)row * 128 + cb;
    ltot += lp[pp * 128 + row];
    for (int q8 = 0; q8 < 4; ++q8) {
      ushort8 v = *(const ushort8*)(ys + q8 * 8);
      for (int j = 0; j < 8; ++j) acc[q8 * 8 + j] += bf2f(v[j]);
    }
  }
  float inv = 1.f / ltot;
  unsigned short* dst = y + (long)(qt * 128 + row) * 1024 + h * 128 + cb;
  for (int q8 = 0; q8 < 4; ++q8) {
    ushort8 o;
    for (int j = 0; j < 8; ++j) o[j] = f2bf(acc[q8 * 8 + j] * inv);
    *(ushort8*)(dst + q8 * 8) = o;
  }
}

// ---------------------------------------------------------------------------
// Workspace layout (bytes), ~42 MB. Attention partials reuse dead regions:
//   0        : qkv_bf (12MB)  | attn: Yp bf16 8*72*32KB = 18.87MB (0..18.87M)
//   12582912 : x_bf   (4MB)   | attn: lp fp32 @18874368 (295KB)
//   16777216 : wqkv   (6MB)
//   23068672 : wproj  (2MB, live until GEMM2)
//   25165824 : qhat [8][2048][128] (4MB)
//   29360128 : khat (4MB)
//   33554432 : vt   [8][128][2048] interleaved (4MB)
//   37748736 : ybf  [2048][1024] (4MB)
// ---------------------------------------------------------------------------
extern "C" void kernel_launch(void* const* d_in, const int* in_sizes, int n_in,
                              void* d_out, int out_size, void* d_ws, size_t ws_size,
                              hipStream_t stream) {
  const float* x       = (const float*)d_in[0];
  const float* ve      = (const float*)d_in[1];
  const float* qkv_w   = (const float*)d_in[2];
  const float* lambdas = (const float*)d_in[3];
  const float* c_proj  = (const float*)d_in[4];
  char* ws = (char*)d_ws;
  unsigned short* qkv_bf = (unsigned short*)(ws);
  unsigned short* x_bf   = (unsigned short*)(ws + 12582912);
  unsigned short* wqkv   = (unsigned short*)(ws + 16777216);
  unsigned short* wproj  = (unsigned short*)(ws + 23068672);
  unsigned short* qhat   = (unsigned short*)(ws + 25165824);
  unsigned short* khat   = (unsigned short*)(ws + 29360128);
  unsigned short* vtb    = (unsigned short*)(ws + 33554432);
  unsigned short* ybf    = (unsigned short*)(ws + 37748736);
  unsigned short* Yp     = (unsigned short*)(ws);              // reuse, 18.9MB
  float*          lpart  = (float*)(ws + 18874368);            // reuse, 295KB
  float* out = (float*)d_out;

  cast3_kernel<<<6144, 256, 0, stream>>>(x, qkv_w, c_proj, x_bf);
  gemm_bt4<true, 64, 128><<<dim3(24, 32), 256, 0, stream>>>(x_bf, wqkv, qkv_bf, 2048, 3072, 1024);
  prep_qkv<<<dim3(32, 8), 256, 0, stream>>>(qkv_bf, ve, lambdas, qhat, khat, vtb);
  attn_part<<<dim3(16, 8, 8), 256, 0, stream>>>(qhat, khat, vtb, Yp, lpart);
  attn_combine<<<dim3(32, 8), 256, 0, stream>>>(Yp, lpart, ybf);
  gemm_bt4<false, 64, 64><<<dim3(16, 32), 256, 0, stream>>>(ybf, wproj, out, 2048, 1024, 1024);
}